// Round 1
// 434.812 us; speedup vs baseline: 1.1188x; 1.1188x over previous
//
#include <hip/hip_runtime.h>
#include <math.h>

// Problem constants (from reference): B=16, D=64, H=160, W=320, T=20
#define BDIM 16
#define DDIM 64
#define TDIM 20
#define NDIM (160*320)   // 51200 spatial positions

#define NEG_HUGE (-3.402823466e38f)

typedef float f2 __attribute__((ext_vector_type(2)));

// ---- Common tiling: 512 n per block, 256 threads, 2 consecutive n per thread.
// Rationale (rocprof R0): old 1024-chunk/4-n-per-thread version offered only
// 800 blocks = 12.5 waves/CU and carried acc[20][4]=80 VGPRs; measured
// Occupancy 18%, VALUBusy 13%, HBM 36% -> latency-bound. Halving per-thread
// work doubles the grid (1600 blocks, 25 waves/CU) and halves acc regs.
constexpr int K_THREADS = 256;
constexpr int K_CHUNK   = 512;
constexpr int K_NB      = NDIM / K_CHUNK;   // 100 (exact)

// ---- Kernel 1: per-chunk online-softmax stats over the spatial axis ----
// grid = (K_NB, B), block = 256. Each thread owns 2 consecutive n (float2).
__global__ __launch_bounds__(K_THREADS)
void k_stats(const float* __restrict__ x1,
             const float* __restrict__ tok,      // [T, D]
             float* __restrict__ pstats)         // [K_NB][B][T][2] = (M, S)
{
    const int b   = blockIdx.y;
    const int nb  = blockIdx.x;
    const int tid = threadIdx.x;
    const int n0  = nb * K_CHUNK + tid * 2;
    const float* xb = x1 + (size_t)b * DDIM * NDIM + n0;

    float a0[TDIM], a1[TDIM];
#pragma unroll
    for (int t = 0; t < TDIM; ++t) { a0[t] = 0.f; a1[t] = 0.f; }

    // scores_t[n..n+1] = sum_d x1[d] * tok[t][d]; tok index wave-uniform -> s_load
#pragma unroll 8
    for (int d = 0; d < DDIM; ++d) {
        const f2 v = *(const f2*)(xb + (size_t)d * NDIM);
#pragma unroll
        for (int t = 0; t < TDIM; ++t) {
            const float tk = tok[t * DDIM + d];
            a0[t] = fmaf(v.x, tk, a0[t]);
            a1[t] = fmaf(v.y, tk, a1[t]);
        }
    }

    // per-thread softmax stats over its 2 n's
    float m[TDIM], s[TDIM];
#pragma unroll
    for (int t = 0; t < TDIM; ++t) {
        const float mm = fmaxf(a0[t], a1[t]);
        m[t] = mm;
        s[t] = __expf(a0[t] - mm) + __expf(a1[t] - mm);
    }

    // wave64 butterfly merge of (m,s) per t
#pragma unroll
    for (int t = 0; t < TDIM; ++t) {
        float mm = m[t], ss = s[t];
        for (int off = 32; off; off >>= 1) {
            const float m2 = __shfl_xor(mm, off);
            const float s2 = __shfl_xor(ss, off);
            const float mx = fmaxf(mm, m2);
            ss = ss * __expf(mm - mx) + s2 * __expf(m2 - mx);
            mm = mx;
        }
        m[t] = mm; s[t] = ss;
    }

    // cross-wave merge (4 waves) via LDS
    __shared__ float red[4][TDIM][2];
    const int wave = tid >> 6;
    const int lane = tid & 63;
    if (lane == 0) {
#pragma unroll
        for (int t = 0; t < TDIM; ++t) {
            red[wave][t][0] = m[t];
            red[wave][t][1] = s[t];
        }
    }
    __syncthreads();
    if (tid < TDIM) {
        float mm = red[0][tid][0], ss = red[0][tid][1];
#pragma unroll
        for (int w = 1; w < 4; ++w) {
            const float m2 = red[w][tid][0], s2 = red[w][tid][1];
            const float mx = fmaxf(mm, m2);
            ss = ss * __expf(mm - mx) + s2 * __expf(m2 - mx);
            mm = mx;
        }
        float* o = pstats + ((size_t)(nb * BDIM + b) * TDIM + tid) * 2;
        o[0] = mm;
        o[1] = ss;
    }
}

// ---- Kernel 2: merge the K_NB partials per (b,t) in parallel ----
// grid = (B, T), block = 64 (one wave). Lane l owns chunks l, l+64 (K_NB=100).
__global__ __launch_bounds__(64)
void k_merge(const float* __restrict__ pstats,
             const int* __restrict__ mask,   // [T]
             float* __restrict__ stats)      // [B][T][2] = (M, C)
{
    const int b = blockIdx.x;
    const int t = blockIdx.y;
    const int l = threadIdx.x;

    float mm = NEG_HUGE, ss = 0.f;
    for (int c = l; c < K_NB; c += 64) {
        const float* p = pstats + ((size_t)(c * BDIM + b) * TDIM + t) * 2;
        const float m2 = p[0], s2 = p[1];
        const float mx = fmaxf(mm, m2);
        ss = ss * __expf(mm - mx) + s2 * __expf(m2 - mx);
        mm = mx;
    }
    // butterfly merge across the wave; identity (NEG_HUGE, 0) is absorbing.
    for (int off = 32; off; off >>= 1) {
        const float m2 = __shfl_xor(mm, off);
        const float s2 = __shfl_xor(ss, off);
        const float mx = fmaxf(mm, m2);
        ss = ss * __expf(mm - mx) + s2 * __expf(m2 - mx);
        mm = mx;
    }
    if (l == 0) {
        float cnt = 0.f;
#pragma unroll
        for (int tt = 0; tt < TDIM; ++tt) cnt += (float)mask[tt];
        const float c = (float)mask[t] / (ss * cnt);
        stats[(b * TDIM + t) * 2 + 0] = mm;
        stats[(b * TDIM + t) * 2 + 1] = c;
    }
}

// ---- Kernel 3: recompute scores, form weight, scale & write out ----
// grid = (K_NB, B), block = 256; each thread owns 2 consecutive n (float2).
// Pass 1 computes the weight, pass 2 re-loads x1 (L2-hot within the block)
// and writes out with NONTEMPORAL stores so the write stream does not evict
// x1 from L3 (pass-1 reads of other blocks want those lines, populated by
// k_stats). Compiler barrier between passes prevents CSE of the loads.
__global__ __launch_bounds__(K_THREADS)
void k_out(const float* __restrict__ x1,
           const float* __restrict__ tok,
           const float* __restrict__ stats,   // [B][T][2] = (M, C)
           float* __restrict__ out)
{
    const int b  = blockIdx.y;
    const int n0 = blockIdx.x * K_CHUNK + threadIdx.x * 2;
    const size_t base = (size_t)b * DDIM * NDIM + n0;

    float a0[TDIM], a1[TDIM];
#pragma unroll
    for (int t = 0; t < TDIM; ++t) { a0[t] = 0.f; a1[t] = 0.f; }

#pragma unroll 8
    for (int d = 0; d < DDIM; ++d) {
        const f2 v = *(const f2*)(x1 + base + (size_t)d * NDIM);
#pragma unroll
        for (int t = 0; t < TDIM; ++t) {
            const float tk = tok[t * DDIM + d];
            a0[t] = fmaf(v.x, tk, a0[t]);
            a1[t] = fmaf(v.y, tk, a1[t]);
        }
    }

    float w0 = 0.f, w1 = 0.f;
#pragma unroll
    for (int t = 0; t < TDIM; ++t) {
        const float M = stats[(b * TDIM + t) * 2 + 0];   // wave-uniform -> s_load
        const float C = stats[(b * TDIM + t) * 2 + 1];
        w0 = fmaf(__expf(a0[t] - M), C, w0);
        w1 = fmaf(__expf(a1[t] - M), C, w1);
    }

    // prevent the compiler from CSE-ing pass-2 loads with pass-1 loads
    __asm__ __volatile__("" ::: "memory");

#pragma unroll 8
    for (int d = 0; d < DDIM; ++d) {
        f2 v = *(const f2*)(x1 + base + (size_t)d * NDIM);
        f2 r;
        r.x = v.x * w0;
        r.y = v.y * w1;
        __builtin_nontemporal_store(r, (f2*)(out + base + (size_t)d * NDIM));
    }
}

extern "C" void kernel_launch(void* const* d_in, const int* in_sizes, int n_in,
                              void* d_out, int out_size, void* d_ws, size_t ws_size,
                              hipStream_t stream)
{
    const float* x1   = (const float*)d_in[0];   // [B, D, H, W]
    const float* x2   = (const float*)d_in[1];   // [1, T, D]
    const int*   mask = (const int*)d_in[2];     // [1, T]
    float* out = (float*)d_out;

    float* pstats = (float*)d_ws;                                   // K_NB*B*T*2 floats (256 KB)
    float* stats  = pstats + (size_t)K_NB * BDIM * TDIM * 2;        // B*T*2 floats

    k_stats<<<dim3(K_NB, BDIM), K_THREADS, 0, stream>>>(x1, x2, pstats);
    k_merge<<<dim3(BDIM, TDIM), 64, 0, stream>>>(pstats, mask, stats);
    k_out<<<dim3(K_NB, BDIM), K_THREADS, 0, stream>>>(x1, x2, stats, out);
}